// Round 5
// baseline (382.262 us; speedup 1.0000x reference)
//
#include <hip/hip_runtime.h>

// FeatureSelfAttention: B=32, T=2048, F=64
// out[b,t,i]    = x[b,t,i] + gamma[i] * mixed[b,t,i]
// attn[b,t,i,j] = softmax_j( q_i * k_j / 8 )
// q = x @ Wq^T, k = x @ Wk^T per position.
//
// One wave per position (round-robin t = gw + r*nw, as in R2). Lane i owns
// row i for pass 1. attn written coalesced: 4 rows x 16 lanes, contiguous
// 1 KB float4 wave-stores. No max-subtraction (|score| <= ~1.3 provably).
//
// R5: software-pipelined. The 16-iteration inner loop fuses
//   pass2 stores of position t   (exp2(qs*k + log2inv) -> attn)
//   pass1 sums  of position t+1  (exp2, sum/mix accumulation)
// so the wave issues one 1 KB store every ~60-70 cycles for most of the
// loop instead of clustering all 16 stores in a pass-2-only phase.
// Theory: chip-wide bursty store duty cycle (~50-60%) is why R2 ran at
// 4.9 TB/s vs fill's 6.5 TB/s. LDS (k, x, ql) double-buffered per wave.
// nt stores and chunked mapping reverted (R4 showed them neutral-negative).

#define LOG2E 1.4426950408889634f

constexpr int F = 64;

typedef _Float16 h2v __attribute__((ext_vector_type(2)));

#if defined(__has_builtin)
#if __has_builtin(__builtin_amdgcn_fdot2)
#define HAVE_FDOT2 1
#endif
#endif

static __device__ __forceinline__ float fdot2(h2v a, h2v b, float c) {
#ifdef HAVE_FDOT2
    return __builtin_amdgcn_fdot2(a, b, c, false);
#else
    return c + (float)a[0] * (float)b[0] + (float)a[1] * (float)b[1];
#endif
}

__global__ __launch_bounds__(256, 4)
void fsattn(const float* __restrict__ X,
            const float* __restrict__ Wq,
            const float* __restrict__ Wk,
            const float* __restrict__ gamma,
            float* __restrict__ out,
            float* __restrict__ attn,
            int BT)
{
    const int lane = threadIdx.x & 63;
    const int wid  = threadIdx.x >> 6;          // wave within block (0..3)
    const int gw   = (blockIdx.x << 2) + wid;   // global wave id
    const int nw   = gridDim.x << 2;

    // per-wave double-buffered scratch; no cross-wave sharing
    __shared__ float    x_lds[4][2][F];
    __shared__ _Float16 xh_lds[4][2][F];
    __shared__ float    k_lds[4][2][F];
    __shared__ float2   ql_lds[4][2][F];        // {qs, log2(inv)} per row

    // lane i holds row i of Wq/Wk as packed f16 pairs: 32+32 VGPRs
    h2v wq2[32], wk2[32];
#pragma unroll
    for (int p = 0; p < 32; ++p) {
        const float2 a = reinterpret_cast<const float2*>(Wq + lane * F)[p];
        const float2 b = reinterpret_cast<const float2*>(Wk + lane * F)[p];
        h2v ha; ha[0] = (_Float16)a.x; ha[1] = (_Float16)a.y;
        h2v hb; hb[0] = (_Float16)b.x; hb[1] = (_Float16)b.y;
        wq2[p] = ha; wk2[p] = hb;
    }
    const float g = gamma[lane];
    const int sub = lane >> 4;
    const int c16 = lane & 15;

    if (gw >= BT) return;

    // ---------------- prologue: full pass1 for t0 = gw into buf 0 ----------
    int buf = 0;
    int tprev = gw;
    float xv = X[(size_t)gw * F + lane];
    float xnext = (gw + nw < BT) ? X[(size_t)(gw + nw) * F + lane] : 0.f;
    {
        x_lds[wid][0][lane]  = xv;
        xh_lds[wid][0][lane] = (_Float16)xv;
        __builtin_amdgcn_wave_barrier();
        float q = 0.f, k = 0.f;
        const h2v* xh = reinterpret_cast<const h2v*>(xh_lds[wid][0]);
#pragma unroll
        for (int p = 0; p < 32; ++p) {
            const h2v xp = xh[p];
            q = fdot2(wq2[p], xp, q);
            k = fdot2(wk2[p], xp, k);
        }
        const float qs = q * (0.125f * LOG2E);
        k_lds[wid][0][lane] = k;
        __builtin_amdgcn_wave_barrier();

        float sum = 0.f, mix = 0.f;
#pragma unroll
        for (int j = 0; j < 16; ++j) {
            const float4 k4 = reinterpret_cast<const float4*>(k_lds[wid][0])[j];
            const float4 x4 = reinterpret_cast<const float4*>(x_lds[wid][0])[j];
            const float e0 = __builtin_amdgcn_exp2f(qs * k4.x);
            const float e1 = __builtin_amdgcn_exp2f(qs * k4.y);
            const float e2 = __builtin_amdgcn_exp2f(qs * k4.z);
            const float e3 = __builtin_amdgcn_exp2f(qs * k4.w);
            sum += (e0 + e1) + (e2 + e3);
            mix = __builtin_fmaf(e0, x4.x, __builtin_fmaf(e1, x4.y,
                  __builtin_fmaf(e2, x4.z, __builtin_fmaf(e3, x4.w, mix))));
        }
        const float inv = __builtin_amdgcn_rcpf(sum);
        const float li  = -__builtin_amdgcn_logf(sum);
        float2 ql; ql.x = qs; ql.y = li;
        ql_lds[wid][0][lane] = ql;
        __builtin_amdgcn_wave_barrier();
        out[(size_t)gw * F + lane] = xv + g * (mix * inv);
    }

    // ---------------- main loop: pass2(tprev) fused with pass1(t) ----------
    for (int t = gw + nw; t < BT; t += nw) {
        const int nbuf = buf ^ 1;
        xv = xnext;
        xnext = (t + nw < BT) ? X[(size_t)(t + nw) * F + lane] : 0.f;

        // phase A: stage x(t), matvec -> q,k
        x_lds[wid][nbuf][lane]  = xv;
        xh_lds[wid][nbuf][lane] = (_Float16)xv;
        __builtin_amdgcn_wave_barrier();
        float q = 0.f, k = 0.f;
        const h2v* xh = reinterpret_cast<const h2v*>(xh_lds[wid][nbuf]);
#pragma unroll
        for (int p = 0; p < 32; ++p) {
            const h2v xp = xh[p];
            q = fdot2(wq2[p], xp, q);
            k = fdot2(wk2[p], xp, k);
        }
        const float qs = q * (0.125f * LOG2E);
        k_lds[wid][nbuf][lane] = k;
        __builtin_amdgcn_wave_barrier();

        // phase B: fused 16 iterations
        float* ap = attn + (size_t)tprev * (F * F);
        const float4 kc = reinterpret_cast<const float4*>(k_lds[wid][buf])[c16];
        float sum = 0.f, mix = 0.f;
#pragma unroll
        for (int j = 0; j < 16; ++j) {
            // pass1 chunk for t
            const float4 k4 = reinterpret_cast<const float4*>(k_lds[wid][nbuf])[j];
            const float4 x4 = reinterpret_cast<const float4*>(x_lds[wid][nbuf])[j];
            const float e0 = __builtin_amdgcn_exp2f(qs * k4.x);
            const float e1 = __builtin_amdgcn_exp2f(qs * k4.y);
            const float e2 = __builtin_amdgcn_exp2f(qs * k4.z);
            const float e3 = __builtin_amdgcn_exp2f(qs * k4.w);
            sum += (e0 + e1) + (e2 + e3);
            mix = __builtin_fmaf(e0, x4.x, __builtin_fmaf(e1, x4.y,
                  __builtin_fmaf(e2, x4.z, __builtin_fmaf(e3, x4.w, mix))));

            // pass2 store for tprev: rows 4j..4j+3, 1 KB contiguous
            const int row = 4 * j + sub;
            const float2 qr = ql_lds[wid][buf][row];   // broadcast ds_read_b64
            float4 w;
            w.x = __builtin_amdgcn_exp2f(__builtin_fmaf(qr.x, kc.x, qr.y));
            w.y = __builtin_amdgcn_exp2f(__builtin_fmaf(qr.x, kc.y, qr.y));
            w.z = __builtin_amdgcn_exp2f(__builtin_fmaf(qr.x, kc.z, qr.y));
            w.w = __builtin_amdgcn_exp2f(__builtin_fmaf(qr.x, kc.w, qr.y));
            reinterpret_cast<float4*>(ap + (size_t)row * F)[c16] = w;
        }

        // phase C: finalize t
        const float inv = __builtin_amdgcn_rcpf(sum);
        const float li  = -__builtin_amdgcn_logf(sum);
        float2 ql; ql.x = qs; ql.y = li;
        ql_lds[wid][nbuf][lane] = ql;
        __builtin_amdgcn_wave_barrier();
        out[(size_t)t * F + lane] = xv + g * (mix * inv);

        tprev = t;
        buf = nbuf;
    }

    // ---------------- epilogue: pass2 for the last position ----------------
    {
        float* ap = attn + (size_t)tprev * (F * F);
        const float4 kc = reinterpret_cast<const float4*>(k_lds[wid][buf])[c16];
#pragma unroll
        for (int j = 0; j < 16; ++j) {
            const int row = 4 * j + sub;
            const float2 qr = ql_lds[wid][buf][row];
            float4 w;
            w.x = __builtin_amdgcn_exp2f(__builtin_fmaf(qr.x, kc.x, qr.y));
            w.y = __builtin_amdgcn_exp2f(__builtin_fmaf(qr.x, kc.y, qr.y));
            w.z = __builtin_amdgcn_exp2f(__builtin_fmaf(qr.x, kc.z, qr.y));
            w.w = __builtin_amdgcn_exp2f(__builtin_fmaf(qr.x, kc.w, qr.y));
            reinterpret_cast<float4*>(ap + (size_t)row * F)[c16] = w;
        }
    }
}

extern "C" void kernel_launch(void* const* d_in, const int* in_sizes, int n_in,
                              void* d_out, int out_size, void* d_ws, size_t ws_size,
                              hipStream_t stream) {
    const float* X     = (const float*)d_in[0];
    const float* Wq    = (const float*)d_in[1];
    const float* Wk    = (const float*)d_in[2];
    const float* gamma = (const float*)d_in[3];

    const int BT = in_sizes[0] / F;              // 65536 positions
    float* out  = (float*)d_out;                 // (B,T,F) first
    float* attn = out + (size_t)BT * F;          // then (B,T,F,F)

    dim3 grid(1024), block(256);
    hipLaunchKernelGGL(fsattn, grid, block, 0, stream,
                       X, Wq, Wk, gamma, out, attn, BT);
}